// Round 9
// baseline (1921.772 us; speedup 1.0000x reference)
//
#include <hip/hip_runtime.h>
#include <math.h>

// Problem constants
#define NG   12
#define Bb   8
#define Ss   1280
#define Cc   512
#define BS   10240            // B*S
#define SC   655360           // S*C per batch
#define OUT0 5242880          // B*S*C floats (output 0)

typedef __bf16 bf16x8 __attribute__((ext_vector_type(8)));
typedef __bf16 bf16x4v __attribute__((ext_vector_type(4)));
typedef float  f32x4  __attribute__((ext_vector_type(4)));

#define GLOAD16(gp, lp)                                                        \
    __builtin_amdgcn_global_load_lds(                                          \
        (const __attribute__((address_space(1))) void*)(gp),                   \
        (__attribute__((address_space(3))) void*)(lp), 16, 0, 0)

__device__ __forceinline__ float fexp2(float x) {
    float r;
    asm("v_exp_f32 %0, %1" : "=v"(r) : "v"(x));
    return r;
}

// ---------------------------------------------------------------------------
__global__ __launch_bounds__(256) void compute_pos(const float* __restrict__ box,
                                                   float4* __restrict__ posr) {
    int i = blockIdx.x * 256 + threadIdx.x;
    if (i < BS) {
        float x0 = box[i * 4 + 0], y0 = box[i * 4 + 1];
        float x1 = box[i * 4 + 2], y1 = box[i * 4 + 3];
        float cx = (x0 + x1) * 0.5f;
        float cy = (y0 + y1) * 0.5f;
        float px = __fmul_rn(cx, cx);
        float py = __fmul_rn(cy, cy);
        posr[i] = make_float4(cx, cy, __fadd_rn(px, py), 0.0f);
    }
}

// ---------------------------------------------------------------------------
__global__ __launch_bounds__(256) void cvt_bf16(const float* __restrict__ src,
                                                __bf16* __restrict__ dst, int n4) {
    for (int i = blockIdx.x * 256 + threadIdx.x; i < n4; i += gridDim.x * 256) {
        float4 v = ((const float4*)src)[i];
        bf16x4v o;
        o[0] = (__bf16)v.x; o[1] = (__bf16)v.y; o[2] = (__bf16)v.z; o[3] = (__bf16)v.w;
        *(bf16x4v*)(dst + i * 4) = o;
    }
}

// ---------------------------------------------------------------------------
// Tiled transpose + convert: dst[c][r] (bf16) = src[r][c] (f32). 64x64 tiles.
// ---------------------------------------------------------------------------
__global__ __launch_bounds__(256) void transpose_cvt(
    const float* __restrict__ src, __bf16* __restrict__ dst,
    int ldsrc, int lddst, long long sSrc, long long sDst) {
    src += sSrc * blockIdx.z;
    dst += sDst * blockIdx.z;
    __shared__ float tile[64][65];
    const int t = threadIdx.x, tx = t & 15, ty = t >> 4;
    const int r0 = blockIdx.x * 64, c0 = blockIdx.y * 64;
#pragma unroll
    for (int rr = 0; rr < 4; ++rr) {
        int r = ty + rr * 16;
        float4 v = *(const float4*)(src + (long long)(r0 + r) * ldsrc + c0 + tx * 4);
        tile[r][tx * 4 + 0] = v.x;
        tile[r][tx * 4 + 1] = v.y;
        tile[r][tx * 4 + 2] = v.z;
        tile[r][tx * 4 + 3] = v.w;
    }
    __syncthreads();
#pragma unroll
    for (int rr = 0; rr < 4; ++rr) {
        int c = ty + rr * 16;
        bf16x4v o;
        o[0] = (__bf16)tile[tx * 4 + 0][c];
        o[1] = (__bf16)tile[tx * 4 + 1][c];
        o[2] = (__bf16)tile[tx * 4 + 2][c];
        o[3] = (__bf16)tile[tx * 4 + 3][c];
        *(bf16x4v*)(dst + (long long)(c0 + c) * lddst + r0 + tx * 4) = o;
    }
}

// ---------------------------------------------------------------------------
// bias rank-1 prep (exact; zeros for this input)
// ---------------------------------------------------------------------------
__global__ __launch_bounds__(256) void uvc_w(
    const float* __restrict__ Wth, const float* __restrict__ Wph,
    const float* __restrict__ bth, const float* __restrict__ bph,
    float* __restrict__ w1w2) {
    const int i = blockIdx.y;
    const int w = threadIdx.x >> 6, l = threadIdx.x & 63;
    const int c = blockIdx.x * 4 + w;
    const float* Wt = Wth + (long long)i * 262144 + (long long)c * 512;
    const float* Wp = Wph + (long long)i * 262144 + (long long)c * 512;
    const float* bt = bth + i * 512;
    const float* bp = bph + i * 512;
    float s1 = 0.f, s2 = 0.f;
#pragma unroll
    for (int e = 0; e < 8; ++e) {
        int f = l + 64 * e;
        s1 = fmaf(Wt[f], bp[f], s1);
        s2 = fmaf(Wp[f], bt[f], s2);
    }
#pragma unroll
    for (int o = 32; o > 0; o >>= 1) { s1 += __shfl_down(s1, o); s2 += __shfl_down(s2, o); }
    if (l == 0) { w1w2[i * 1024 + c] = s1; w1w2[i * 1024 + 512 + c] = s2; }
}

__global__ void cvals_k(const float* __restrict__ bth, const float* __restrict__ bph,
                        float* __restrict__ cvals) {
    const int i = blockIdx.x;
    const int l = threadIdx.x;  // 64
    float s = 0.f;
#pragma unroll
    for (int e = 0; e < 8; ++e)
        s = fmaf(bth[i * 512 + l + 64 * e], bph[i * 512 + l + 64 * e], s);
#pragma unroll
    for (int o = 32; o > 0; o >>= 1) s += __shfl_down(s, o);
    if (l == 0) cvals[i] = s;
}

__global__ __launch_bounds__(256) void uvc_x(
    const float* __restrict__ x, const float* __restrict__ w1w2,
    float* __restrict__ u, float* __restrict__ v) {
    __shared__ float wv[24][512];
    const int t = threadIdx.x;
    for (int idx = t; idx < 3072; idx += 256) {
        int j = idx >> 7, c4 = idx & 127;
        const float* src = (j < 12) ? (w1w2 + j * 1024 + c4 * 4)
                                    : (w1w2 + (j - 12) * 1024 + 512 + c4 * 4);
        *(float4*)&wv[j][c4 * 4] = *(const float4*)src;
    }
    __syncthreads();
    const int w = t >> 6, l = t & 63;
    const int row = blockIdx.x * 4 + w;
    float xv[8];
#pragma unroll
    for (int e = 0; e < 8; ++e) xv[e] = x[(long long)row * 512 + l + 64 * e];
#pragma unroll
    for (int j = 0; j < 24; ++j) {
        float p = 0.f;
#pragma unroll
        for (int e = 0; e < 8; ++e) p = fmaf(xv[e], wv[j][l + 64 * e], p);
#pragma unroll
        for (int o = 32; o > 0; o >>= 1) p += __shfl_down(p, o);
        if (l == 0) {
            if (j < 12) u[j * BS + row] = p;
            else        v[(j - 12) * BS + row] = p;
        }
    }
}

// ---------------------------------------------------------------------------
// bf16 MFMA GEMM, "nt": C[M][N] = A[M][K] * Bt[N][K]^T (f32 accum)
// 128x128 tile, BK=64, XOR-swizzled LDS, double-buffered 2-phase K-loop,
// 8 waves (512 threads, wave grid 4x2, 32x64 per wave),
// XCD-contiguous block swizzle (total blocks % 8 == 0 required).
// bz splits: bzh = bz/zdiv (graph slot), bzl = bz%zdiv (batch).
// MODE 1: sim: (acc+u+v+c)*scale, mask -> -inf; bf16 (bzh<nbf, log2-scaled)
//         else f32 (scale_f32)
// MODE 2: bf16 out
// MODE 3: PV with FUSED ONLINE SOFTMAX on A (unless bzh==pslot: A is already P):
//         sweep-1 computes per-row max m and 1/sum(2^(s-m)); K-loop converts
//         raw S frags to P=2^(s-m); epilogue multiplies 1/sum; f32 out +
//         fused LN partial stats (atomicAdd per (bzh,bzl)).
// ---------------------------------------------------------------------------
template <int MODE>
__global__ __launch_bounds__(512) void gemm_bf16(
    const __bf16* __restrict__ A, const __bf16* __restrict__ Bt, void* __restrict__ Cv,
    int lda, int ldb, int ldc, int K, int zdiv,
    long long sA_hi, long long sA, long long sB_hi, long long sB,
    long long sC_hi, long long sC,
    const float* __restrict__ uvec, const float* __restrict__ vvec,
    const float* __restrict__ cptr,
    const float4* __restrict__ posr, const int* __restrict__ OWp,
    float scale, float scale_f32,
    __bf16* __restrict__ obf_out, long long sOb, int nbf,
    float* __restrict__ statsraw, int pslot) {

    // XCD-contiguous swizzle
    const int gx = gridDim.x, gy = gridDim.y;
    int id = blockIdx.x + gx * (blockIdx.y + gy * blockIdx.z);
    const int q = (gx * gy * gridDim.z) >> 3;
    id = (id & 7) * q + (id >> 3);
    const int bx = id % gx;
    const int rem = id / gx;
    const int by = rem % gy;
    const int bz = rem / gy;
    const int bzh = bz / zdiv, bzl = bz - bzh * zdiv;

    A += sA_hi * bzh + sA * bzl;
    Bt += sB_hi * bzh + sB * bzl;
    const int m0 = by * 128, n0 = bx * 128;

    __shared__ char lds[66560];  // 2 x (A 16K | B 16K) + mrow 512B + irow 512B

    const int t = threadIdx.x, l = t & 63, w = t >> 6;  // w 0..7
    const int wm = w >> 1, wn = w & 1;                  // 4x2 wave grid

    const bool fused = (MODE == 3) && (bzh != pslot);

    // ---- sweep-1 (fused softmax): per-row max + inv-sum over full K ----
    if (MODE == 3 && fused) {
        float* mrow = (float*)(lds + 65536);
        float* irow = (float*)(lds + 66048);
        const int r = t >> 2, part = t & 3;
        const __bf16* Sp = A + (long long)(m0 + r) * lda + part * (K >> 2);
        const int NE = K >> 5;  // bf16x8 chunks per quarter-row
        float mx = -INFINITY;
        for (int e = 0; e < NE; ++e) {
            bf16x8 vv = *(const bf16x8*)(Sp + e * 8);
#pragma unroll
            for (int qq = 0; qq < 8; ++qq) mx = fmaxf(mx, (float)vv[qq]);
        }
        mx = fmaxf(mx, __shfl_xor(mx, 1));
        mx = fmaxf(mx, __shfl_xor(mx, 2));
        float sum = 0.f;
        for (int e = 0; e < NE; ++e) {
            bf16x8 vv = *(const bf16x8*)(Sp + e * 8);
#pragma unroll
            for (int qq = 0; qq < 8; ++qq) sum += fexp2((float)vv[qq] - mx);
        }
        sum += __shfl_xor(sum, 1);
        sum += __shfl_xor(sum, 2);
        if (part == 0) { mrow[r] = mx; irow[r] = 1.0f / sum; }
    }

    f32x4 acc[2][4] = {};

    // staging: wave w stages 16 rows of A and B; lane l -> row +(l>>3),
    // LDS granule (l&7) gets source granule (l&7)^(row&7)
    const int g2 = (((l & 7) ^ (l >> 3)) << 4);
    const long long la2 = (long long)lda * 2, lb2 = (long long)ldb * 2;
    const char* Agp = (const char*)A + (long long)(m0 + w * 16 + (l >> 3)) * la2 + g2;
    const char* Bgp = (const char*)Bt + (long long)(n0 + w * 16 + (l >> 3)) * lb2 + g2;

    // fragment reads: row ...+fr, granule g=ks*4+qh at slot g^(row&7)
    const int fr = l & 15, qh = l >> 4, sx = l & 7;
    int offA[2][2], offB[2][4];
#pragma unroll
    for (int ks = 0; ks < 2; ++ks) {
        const int swz = (((ks << 2) | qh) ^ sx) << 4;
#pragma unroll
        for (int i = 0; i < 2; ++i)
            offA[ks][i] = (wm * 32 + i * 16 + fr) * 128 + swz;
#pragma unroll
        for (int j = 0; j < 4; ++j)
            offB[ks][j] = 16384 + (wn * 64 + j * 16 + fr) * 128 + swz;
    }

#define STAGE(kt, bufo)                                                        \
    {                                                                          \
        const long long kb = (long long)(kt) * 128;                            \
        char* lA = lds + (bufo) + w * 2048;                                    \
        char* lB = lds + (bufo) + 16384 + w * 2048;                            \
        GLOAD16(Agp + kb, lA);                                                 \
        GLOAD16(Agp + kb + 8 * la2, lA + 1024);                                \
        GLOAD16(Bgp + kb, lB);                                                 \
        GLOAD16(Bgp + kb + 8 * lb2, lB + 1024);                                \
    }

    const int KT = K >> 6;
    STAGE(0, 0);
    __syncthreads();

    // hoist per-fragment row max (LDS, valid after the barrier above)
    float mA0 = 0.f, mA1 = 0.f;
    if (MODE == 3 && fused) {
        const float* mrow = (const float*)(lds + 65536);
        mA0 = mrow[wm * 32 + fr];
        mA1 = mrow[wm * 32 + 16 + fr];
    }

    for (int kt = 0; kt < KT; ++kt) {
        const int cur = (kt & 1) << 15;
        if (kt + 1 < KT) STAGE(kt + 1, cur ^ 32768);
#pragma unroll
        for (int ks = 0; ks < 2; ++ks) {
            bf16x8 af[2], bfr[4];
#pragma unroll
            for (int i = 0; i < 2; ++i) {
                bf16x8 raw = *(const bf16x8*)(lds + cur + offA[ks][i]);
                if (MODE == 3 && fused) {
                    const float mm = i ? mA1 : mA0;
                    bf16x8 pv;
#pragma unroll
                    for (int qq = 0; qq < 8; ++qq)
                        pv[qq] = (__bf16)fexp2((float)raw[qq] - mm);
                    af[i] = pv;
                } else {
                    af[i] = raw;
                }
            }
#pragma unroll
            for (int j = 0; j < 4; ++j) bfr[j] = *(const bf16x8*)(lds + cur + offB[ks][j]);
#pragma unroll
            for (int i = 0; i < 2; ++i)
#pragma unroll
                for (int j = 0; j < 4; ++j)
                    acc[i][j] = __builtin_amdgcn_mfma_f32_16x16x32_bf16(
                        af[i], bfr[j], acc[i][j], 0, 0, 0);
        }
        __syncthreads();
    }
#undef STAGE

    // C/D frag: col = n0+wn*64+j*16+(l&15), row = m0+wm*32+i*16+(l>>4)*4+r
    const int crow0 = m0 + wm * 32 + (l >> 4) * 4;
    const int ccol0 = n0 + wn * 64 + fr;

    if (MODE == 1) {
        const float4* pr = posr + bzl * Ss;
        const float* uv = uvec + (long long)bzh * BS + bzl * Ss;
        const float* vv = vvec + (long long)bzh * BS + bzl * Ss;
        const float cadd = cptr[bzh];
        const float thr = 0.2f * (float)(*OWp);
        float4 pm[4];
        float vj[4];
#pragma unroll
        for (int j = 0; j < 4; ++j) {
            pm[j] = pr[ccol0 + j * 16];
            vj[j] = vv[ccol0 + j * 16];
        }
        float* Cf = (float*)Cv + sC * bzl;
        __bf16* Cb = obf_out + sOb * bzh + sC * bzl;
        const int as_bf = (bzh < nbf);
#pragma unroll
        for (int i = 0; i < 2; ++i)
#pragma unroll
            for (int r = 0; r < 4; ++r) {
                int row = crow0 + i * 16 + r;
                float4 pn = pr[row];
                float un = uv[row];
#pragma unroll
                for (int j = 0; j < 4; ++j) {
                    float e = fmaf(pn.y, pm[j].y, pn.x * pm[j].x);
                    float d2 = __fadd_rn(__fsub_rn(pn.z, __fmul_rn(2.0f, e)), pm[j].z);
                    float dist = sqrtf(fmaxf(d2, 0.0f));
                    float base = acc[i][j][r] + un + vj[j] + cadd;
                    if (as_bf) {
                        float ov = base * scale;
                        if (dist > thr) ov = -INFINITY;
                        Cb[(long long)row * ldc + ccol0 + j * 16] = (__bf16)ov;
                    } else {
                        float ov = base * scale_f32;
                        if (dist > thr) ov = -INFINITY;
                        Cf[(long long)row * ldc + ccol0 + j * 16] = ov;
                    }
                }
            }
    } else if (MODE == 2) {
        __bf16* C = (__bf16*)Cv + sC_hi * bzh + sC * bzl;
#pragma unroll
        for (int j = 0; j < 4; ++j)
#pragma unroll
            for (int i = 0; i < 2; ++i)
#pragma unroll
                for (int r = 0; r < 4; ++r) {
                    int row = crow0 + i * 16 + r;
                    C[(long long)row * ldc + ccol0 + j * 16] = (__bf16)acc[i][j][r];
                }
    } else {
        float* C = (float*)Cv + sC_hi * bzh + sC * bzl;
        const float* irow = (const float*)(lds + 66048);
        const int crl0 = wm * 32 + (l >> 4) * 4;
        float s = 0.f, ss = 0.f;
#pragma unroll
        for (int j = 0; j < 4; ++j)
#pragma unroll
            for (int i = 0; i < 2; ++i)
#pragma unroll
                for (int r = 0; r < 4; ++r) {
                    int row = crow0 + i * 16 + r;
                    float ov = acc[i][j][r];
                    if (fused) ov *= irow[crl0 + i * 16 + r];
                    C[(long long)row * ldc + ccol0 + j * 16] = ov;
                    s += ov;
                    ss = fmaf(ov, ov, ss);
                }
#pragma unroll
        for (int o = 32; o > 0; o >>= 1) {
            s += __shfl_down(s, o);
            ss += __shfl_down(ss, o);
        }
        float* redf = (float*)lds;
        if (l == 0) { redf[w * 2] = s; redf[w * 2 + 1] = ss; }
        __syncthreads();
        if (t == 0) {
            float S = 0.f, SS = 0.f;
#pragma unroll
            for (int ww = 0; ww < 8; ++ww) { S += redf[ww * 2]; SS += redf[ww * 2 + 1]; }
            atomicAdd(&statsraw[(bzh * zdiv + bzl) * 2], S);
            atomicAdd(&statsraw[(bzh * zdiv + bzl) * 2 + 1], SS);
        }
    }
}

// ---------------------------------------------------------------------------
// Row softmax (exact f32, last graph only): f32 in-place + bf16 out.
// ---------------------------------------------------------------------------
template <int INBF>
__global__ __launch_bounds__(256) void softmax_rows(
    const __bf16* __restrict__ inbf, float* __restrict__ f32io,
    __bf16* __restrict__ relbf) {
    const int row = blockIdx.x;
    __shared__ float buf[Ss];
    __shared__ float wred[4];
    const int t = threadIdx.x;

    float m = -INFINITY;
    if (INBF) {
        const __bf16* p = inbf + (long long)row * Ss;
        for (int j = t; j < Ss; j += 256) {
            float v = (float)p[j];
            buf[j] = v;
            m = fmaxf(m, v);
        }
    } else {
        const float* p = f32io + (long long)row * Ss;
        for (int j = t; j < Ss; j += 256) {
            float v = p[j];
            buf[j] = v;
            m = fmaxf(m, v);
        }
    }
#pragma unroll
    for (int o = 32; o > 0; o >>= 1) m = fmaxf(m, __shfl_down(m, o));
    if ((t & 63) == 0) wred[t >> 6] = m;
    __syncthreads();
    const float m4 = fmaxf(fmaxf(wred[0], wred[1]), fmaxf(wred[2], wred[3]));
    __syncthreads();

    float s = 0.0f;
    for (int j = t; j < Ss; j += 256) {
        float e = expf(buf[j] - m4);
        buf[j] = e;
        s += e;
    }
#pragma unroll
    for (int o = 32; o > 0; o >>= 1) s += __shfl_down(s, o);
    if ((t & 63) == 0) wred[t >> 6] = s;
    __syncthreads();
    const float total = wred[0] + wred[1] + wred[2] + wred[3];
    const float inv = 1.0f / total;
    __bf16* qo = relbf + (long long)row * Ss;
    float* po = f32io + (long long)row * Ss;
    for (int j = t; j < Ss; j += 256) {
        float v = buf[j] * inv;
        qo[j] = (__bf16)v;
        if (!INBF) po[j] = v;
    }
}

// ---------------------------------------------------------------------------
// finalize 16 (graph-slot, batch) LN stats; reset raw accumulators
// ---------------------------------------------------------------------------
__global__ void stats_final(float* __restrict__ raw, float2* __restrict__ stats) {
    const int b = threadIdx.x;
    if (b < 16) {
        float S = raw[b * 2], SS = raw[b * 2 + 1];
        const float invn = 1.0f / (float)SC;
        float mu = S * invn;
        float var = SS * invn - mu * mu;
        stats[b] = make_float2(mu, 1.0f / sqrtf(var + 1e-5f));
        raw[b * 2] = 0.f;
        raw[b * 2 + 1] = 0.f;
    }
}

// ---------------------------------------------------------------------------
// out (+)= relu(LN(agg_g0)) + relu(LN(agg_g1))  (pair)
// ---------------------------------------------------------------------------
__global__ __launch_bounds__(256) void ln_relu2(
    const float* __restrict__ agg, const float2* __restrict__ stats,
    const float* __restrict__ lnsc, const float* __restrict__ lnbi,
    float* __restrict__ out, int first) {
    for (int idx = blockIdx.x * 256 + threadIdx.x; idx < OUT0 / 4;
         idx += gridDim.x * 256) {
        int b = idx / (SC / 4);
        int j = idx - b * (SC / 4);
        float2 s0 = stats[b], s1 = stats[8 + b];
        float4 a0 = ((const float4*)agg)[idx];
        float4 a1 = ((const float4*)agg)[idx + OUT0 / 4];
        float4 c0 = ((const float4*)lnsc)[j];
        float4 c1 = ((const float4*)(lnsc + SC))[j];
        float4 bi0 = ((const float4*)lnbi)[j];
        float4 bi1 = ((const float4*)(lnbi + SC))[j];
        float4 o;
        o.x = fmaxf((a0.x - s0.x) * s0.y * c0.x + bi0.x, 0.f)
            + fmaxf((a1.x - s1.x) * s1.y * c1.x + bi1.x, 0.f);
        o.y = fmaxf((a0.y - s0.x) * s0.y * c0.y + bi0.y, 0.f)
            + fmaxf((a1.y - s1.x) * s1.y * c1.y + bi1.y, 0.f);
        o.z = fmaxf((a0.z - s0.x) * s0.y * c0.z + bi0.z, 0.f)
            + fmaxf((a1.z - s1.x) * s1.y * c1.z + bi1.z, 0.f);
        o.w = fmaxf((a0.w - s0.x) * s0.y * c0.w + bi0.w, 0.f)
            + fmaxf((a1.w - s1.x) * s1.y * c1.w + bi1.w, 0.f);
        float4* op = (float4*)out + idx;
        if (!first) {
            float4 pv = *op;
            o.x += pv.x; o.y += pv.y; o.z += pv.z; o.w += pv.w;
        }
        *op = o;
    }
}

// ---------------------------------------------------------------------------
extern "C" void kernel_launch(void* const* d_in, const int* in_sizes, int n_in,
                              void* d_out, int out_size, void* d_ws, size_t ws_size,
                              hipStream_t stream) {
    const float* x        = (const float*)d_in[0];
    const float* box      = (const float*)d_in[1];
    const float* W_theta  = (const float*)d_in[2];
    const float* b_theta  = (const float*)d_in[3];
    const float* W_phi    = (const float*)d_in[4];
    const float* b_phi    = (const float*)d_in[5];
    const float* W_gcn    = (const float*)d_in[6];
    const float* ln_scale = (const float*)d_in[7];
    const float* ln_bias  = (const float*)d_in[8];
    const int*   OWp      = (const int*)d_in[10];

    float* out = (float*)d_out;            // [8,1280,512]
    float* rel_f32 = out + OUT0;           // [8,1280,1280] (output 1 region)
    __bf16* simbf = (__bf16*)rel_f32;      // bf16 S pair scratch (non-last groups)

    char* ws = (char*)d_ws;
    float4* posr   = (float4*)(ws + 0);                 //   163840
    __bf16* x_bf   = (__bf16*)(ws + 163840);            // 10485760 [10240][512]
    __bf16* Wgt    = (__bf16*)(ws + 10649600);          //  6291456 [12][512][512]
    __bf16* GiT    = (__bf16*)(ws + 16941056);          //  6291456 [12][512][512]
    float*  w1w2   = (float*)(ws + 23232512);           //    49152
    float*  cvals  = (float*)(ws + 23281664);           //      256
    float*  u      = (float*)(ws + 23281920);           //   491520 [12][10240]
    float*  v      = (float*)(ws + 23773440);           //   491520
    float*  sraw   = (float*)(ws + 24264960);           //      128 (16 slots)
    float2* stats  = (float2*)(ws + 24265088);          //      128
    __bf16* ybuf   = (__bf16*)(ws + 24265216);          // 20971520 [2][10240][512]
    __bf16* z_all  = (__bf16*)(ws + 45236736);          // 125829120 [12][8][512][1280]
    __bf16* S_last = (__bf16*)(ws + 171065856);         // 26214400 [8][1280][1280]
    // relbf_last = S_last + BS*Ss (contiguous; slot stride BS*Ss)  26214400
    float*  aggF   = (float*)(ws + 223494656);          // 41943040 [2][10240][512] f32
    // prep-only aliases (inside aggF region; dead once loop starts)
    __bf16* Wth_bf = (__bf16*)(ws + 223494656);         //  6291456
    __bf16* Wph_bf = (__bf16*)(ws + 229786112);         //  6291456
    __bf16* relbf_last = S_last + (long long)BS * Ss;

    hipMemsetAsync(sraw, 0, 128, stream);

    // ---- one-time prep ----
    compute_pos<<<dim3(40), dim3(256), 0, stream>>>(box, posr);
    cvt_bf16<<<dim3(2048), dim3(256), 0, stream>>>(x, x_bf, OUT0 / 4);
    cvt_bf16<<<dim3(2048), dim3(256), 0, stream>>>(W_theta, Wth_bf, 786432);
    cvt_bf16<<<dim3(2048), dim3(256), 0, stream>>>(W_phi, Wph_bf, 786432);
    transpose_cvt<<<dim3(8, 8, 12), dim3(256), 0, stream>>>(
        W_gcn, Wgt, Cc, Cc, (long long)Cc * Cc, (long long)Cc * Cc);
    // GiT[i][d][c] = sum_f Wphi[d][f] * Wtheta[c][f]
    gemm_bf16<2><<<dim3(4, 4, 12), dim3(512), 0, stream>>>(
        Wph_bf, Wth_bf, GiT, Cc, Cc, Cc, Cc, 1,
        262144, 0, 262144, 0, 262144, 0,
        nullptr, nullptr, nullptr, nullptr, nullptr, 0.f, 0.f, nullptr, 0, 0,
        nullptr, -9);
    // bias rank-1 terms (exact; zeros for this input)
    uvc_w<<<dim3(128, 12), dim3(256), 0, stream>>>(W_theta, W_phi, b_theta, b_phi, w1w2);
    cvals_k<<<dim3(12), dim3(64), 0, stream>>>(b_theta, b_phi, cvals);
    uvc_x<<<dim3(2560), dim3(256), 0, stream>>>(x, w1w2, u, v);
    // z_all[i][b][c][s] = sum_f Wgt_i[c][f] * x_b[s][f]
    gemm_bf16<2><<<dim3(10, 4, 96), dim3(512), 0, stream>>>(
        Wgt, x_bf, z_all, Cc, Cc, Ss, Cc, 8,
        262144, 0, 0, (long long)SC, (long long)Bb * Cc * Ss, (long long)Cc * Ss,
        nullptr, nullptr, nullptr, nullptr, nullptr, 0.f, 0.f, nullptr, 0, 0,
        nullptr, -9);

    const float inv_sqrt = 0.044194173824159216f;       // 1/sqrt(512)
    const float LOG2E = 1.4426950408889634f;

    for (int g = 0; g < 6; ++g) {
        const int i0 = g * 2;
        const int lastg = (g == 5);
        // y pair: ybuf[s][m][c] = x @ G_{i0+s}
        gemm_bf16<2><<<dim3(4, 80, 2), dim3(512), 0, stream>>>(
            x_bf, GiT + (long long)i0 * Cc * Cc, ybuf, Cc, Cc, Cc, Cc, 1,
            0, 0, 262144, 0, (long long)BS * Cc, 0,
            nullptr, nullptr, nullptr, nullptr, nullptr, 0.f, 0.f, nullptr, 0, 0,
            nullptr, -9);
        // sim pair = (y @ x^T + u + v + c), masked; bf16*log2e (fused-softmax
        // slots) or exact f32 (last graph's relation)
        __bf16* obf = lastg ? S_last : simbf;
        gemm_bf16<1><<<dim3(10, 10, 16), dim3(512), 0, stream>>>(
            ybuf, x_bf, rel_f32, Cc, Cc, Ss, Cc, 8,
            (long long)BS * Cc, (long long)Ss * Cc, 0, (long long)Ss * Cc,
            0, (long long)Ss * Ss,
            u + (long long)i0 * BS, v + (long long)i0 * BS, cvals + i0,
            posr, OWp, inv_sqrt * LOG2E, inv_sqrt,
            obf, (long long)BS * Ss, lastg ? 1 : 2, nullptr, -9);
        // exact softmax for the relation output (last graph only)
        if (lastg)
            softmax_rows<0><<<dim3(BS), dim3(256), 0, stream>>>(
                nullptr, rel_f32, relbf_last);
        // agg pair = softmax(S) @ z -> f32 (+ fused LN partial stats)
        const __bf16* Apv = lastg ? S_last : simbf;
        gemm_bf16<3><<<dim3(4, 10, 16), dim3(512), 0, stream>>>(
            Apv, z_all + (long long)i0 * Bb * Cc * Ss, aggF,
            Ss, Ss, Cc, Ss, 8,
            (long long)BS * Ss, (long long)Ss * Ss,
            (long long)Bb * Cc * Ss, (long long)Cc * Ss,
            (long long)BS * Cc, (long long)SC,
            nullptr, nullptr, nullptr, nullptr, nullptr, 0.f, 0.f, nullptr, 0, 0,
            sraw, lastg ? 1 : -1);
        // finalize pair stats (and reset raw accumulators)
        stats_final<<<dim3(1), dim3(64), 0, stream>>>(sraw, stats);
        // out (+)= relu(LN(agg0)) + relu(LN(agg1))
        ln_relu2<<<dim3(2048), dim3(256), 0, stream>>>(
            aggF, stats, ln_scale + (long long)i0 * SC, ln_bias + (long long)i0 * SC,
            out, g == 0 ? 1 : 0);
    }
}

// Round 10
// 1289.432 us; speedup vs baseline: 1.4904x; 1.4904x over previous
//
#include <hip/hip_runtime.h>
#include <math.h>

// Problem constants
#define NG   12
#define Bb   8
#define Ss   1280
#define Cc   512
#define BS   10240            // B*S
#define SC   655360           // S*C per batch
#define OUT0 5242880          // B*S*C floats (output 0)

typedef __bf16 bf16x8 __attribute__((ext_vector_type(8)));
typedef __bf16 bf16x4v __attribute__((ext_vector_type(4)));
typedef float  f32x4  __attribute__((ext_vector_type(4)));

#define GLOAD16(gp, lp)                                                        \
    __builtin_amdgcn_global_load_lds(                                          \
        (const __attribute__((address_space(1))) void*)(gp),                   \
        (__attribute__((address_space(3))) void*)(lp), 16, 0, 0)

// ---------------------------------------------------------------------------
__global__ __launch_bounds__(256) void compute_pos(const float* __restrict__ box,
                                                   float4* __restrict__ posr) {
    int i = blockIdx.x * 256 + threadIdx.x;
    if (i < BS) {
        float x0 = box[i * 4 + 0], y0 = box[i * 4 + 1];
        float x1 = box[i * 4 + 2], y1 = box[i * 4 + 3];
        float cx = (x0 + x1) * 0.5f;
        float cy = (y0 + y1) * 0.5f;
        float px = __fmul_rn(cx, cx);
        float py = __fmul_rn(cy, cy);
        posr[i] = make_float4(cx, cy, __fadd_rn(px, py), 0.0f);
    }
}

// ---------------------------------------------------------------------------
__global__ __launch_bounds__(256) void cvt_bf16(const float* __restrict__ src,
                                                __bf16* __restrict__ dst, int n4) {
    for (int i = blockIdx.x * 256 + threadIdx.x; i < n4; i += gridDim.x * 256) {
        float4 v = ((const float4*)src)[i];
        bf16x4v o;
        o[0] = (__bf16)v.x; o[1] = (__bf16)v.y; o[2] = (__bf16)v.z; o[3] = (__bf16)v.w;
        *(bf16x4v*)(dst + i * 4) = o;
    }
}

// ---------------------------------------------------------------------------
// Tiled transpose + convert: dst[c][r] (bf16) = src[r][c] (f32). 64x64 tiles.
// ---------------------------------------------------------------------------
__global__ __launch_bounds__(256) void transpose_cvt(
    const float* __restrict__ src, __bf16* __restrict__ dst,
    int ldsrc, int lddst, long long sSrc, long long sDst) {
    src += sSrc * blockIdx.z;
    dst += sDst * blockIdx.z;
    __shared__ float tile[64][65];
    const int t = threadIdx.x, tx = t & 15, ty = t >> 4;
    const int r0 = blockIdx.x * 64, c0 = blockIdx.y * 64;
#pragma unroll
    for (int rr = 0; rr < 4; ++rr) {
        int r = ty + rr * 16;
        float4 v = *(const float4*)(src + (long long)(r0 + r) * ldsrc + c0 + tx * 4);
        tile[r][tx * 4 + 0] = v.x;
        tile[r][tx * 4 + 1] = v.y;
        tile[r][tx * 4 + 2] = v.z;
        tile[r][tx * 4 + 3] = v.w;
    }
    __syncthreads();
#pragma unroll
    for (int rr = 0; rr < 4; ++rr) {
        int c = ty + rr * 16;
        bf16x4v o;
        o[0] = (__bf16)tile[tx * 4 + 0][c];
        o[1] = (__bf16)tile[tx * 4 + 1][c];
        o[2] = (__bf16)tile[tx * 4 + 2][c];
        o[3] = (__bf16)tile[tx * 4 + 3][c];
        *(bf16x4v*)(dst + (long long)(c0 + c) * lddst + r0 + tx * 4) = o;
    }
}

// ---------------------------------------------------------------------------
// bias rank-1 prep (exact; zeros for this input)
// ---------------------------------------------------------------------------
__global__ __launch_bounds__(256) void uvc_w(
    const float* __restrict__ Wth, const float* __restrict__ Wph,
    const float* __restrict__ bth, const float* __restrict__ bph,
    float* __restrict__ w1w2) {
    const int i = blockIdx.y;
    const int w = threadIdx.x >> 6, l = threadIdx.x & 63;
    const int c = blockIdx.x * 4 + w;
    const float* Wt = Wth + (long long)i * 262144 + (long long)c * 512;
    const float* Wp = Wph + (long long)i * 262144 + (long long)c * 512;
    const float* bt = bth + i * 512;
    const float* bp = bph + i * 512;
    float s1 = 0.f, s2 = 0.f;
#pragma unroll
    for (int e = 0; e < 8; ++e) {
        int f = l + 64 * e;
        s1 = fmaf(Wt[f], bp[f], s1);
        s2 = fmaf(Wp[f], bt[f], s2);
    }
#pragma unroll
    for (int o = 32; o > 0; o >>= 1) { s1 += __shfl_down(s1, o); s2 += __shfl_down(s2, o); }
    if (l == 0) { w1w2[i * 1024 + c] = s1; w1w2[i * 1024 + 512 + c] = s2; }
}

__global__ void cvals_k(const float* __restrict__ bth, const float* __restrict__ bph,
                        float* __restrict__ cvals) {
    const int i = blockIdx.x;
    const int l = threadIdx.x;  // 64
    float s = 0.f;
#pragma unroll
    for (int e = 0; e < 8; ++e)
        s = fmaf(bth[i * 512 + l + 64 * e], bph[i * 512 + l + 64 * e], s);
#pragma unroll
    for (int o = 32; o > 0; o >>= 1) s += __shfl_down(s, o);
    if (l == 0) cvals[i] = s;
}

__global__ __launch_bounds__(256) void uvc_x(
    const float* __restrict__ x, const float* __restrict__ w1w2,
    float* __restrict__ u, float* __restrict__ v) {
    __shared__ float wv[24][512];
    const int t = threadIdx.x;
    for (int idx = t; idx < 3072; idx += 256) {
        int j = idx >> 7, c4 = idx & 127;
        const float* src = (j < 12) ? (w1w2 + j * 1024 + c4 * 4)
                                    : (w1w2 + (j - 12) * 1024 + 512 + c4 * 4);
        *(float4*)&wv[j][c4 * 4] = *(const float4*)src;
    }
    __syncthreads();
    const int w = t >> 6, l = t & 63;
    const int row = blockIdx.x * 4 + w;
    float xv[8];
#pragma unroll
    for (int e = 0; e < 8; ++e) xv[e] = x[(long long)row * 512 + l + 64 * e];
#pragma unroll
    for (int j = 0; j < 24; ++j) {
        float p = 0.f;
#pragma unroll
        for (int e = 0; e < 8; ++e) p = fmaf(xv[e], wv[j][l + 64 * e], p);
#pragma unroll
        for (int o = 32; o > 0; o >>= 1) p += __shfl_down(p, o);
        if (l == 0) {
            if (j < 12) u[j * BS + row] = p;
            else        v[(j - 12) * BS + row] = p;
        }
    }
}

// ---------------------------------------------------------------------------
// bf16 MFMA GEMM, "nt": C[M][N] = A[M][K] * Bt[N][K]^T (f32 accum)
// 128x128 tile, BK=64, XOR-swizzled LDS, double-buffered 2-phase K-loop,
// 8 waves (512 threads, wave grid 4x2, 32x64 per wave),
// XCD-contiguous block swizzle (total blocks % 8 == 0 required).
// bz splits: bzh = bz/zdiv (graph slot), bzl = bz%zdiv (batch).
// MODE 1: sim: (acc+u+v+c)*scale, mask -> -inf; bf16 out if bzh<nbf else f32
// MODE 2: bf16 out
// MODE 3: bf16 out + fused LN partial stats in f32 (atomicAdd per (bzh,bzl))
// ---------------------------------------------------------------------------
template <int MODE>
__global__ __launch_bounds__(512) void gemm_bf16(
    const __bf16* __restrict__ A, const __bf16* __restrict__ Bt, void* __restrict__ Cv,
    int lda, int ldb, int ldc, int K, int zdiv,
    long long sA_hi, long long sA, long long sB_hi, long long sB,
    long long sC_hi, long long sC,
    const float* __restrict__ uvec, const float* __restrict__ vvec,
    const float* __restrict__ cptr,
    const float4* __restrict__ posr, const int* __restrict__ OWp, float scale,
    __bf16* __restrict__ obf_out, long long sOb, int nbf,
    float* __restrict__ statsraw) {

    // XCD-contiguous swizzle
    const int gx = gridDim.x, gy = gridDim.y;
    int id = blockIdx.x + gx * (blockIdx.y + gy * blockIdx.z);
    const int q = (gx * gy * gridDim.z) >> 3;
    id = (id & 7) * q + (id >> 3);
    const int bx = id % gx;
    const int rem = id / gx;
    const int by = rem % gy;
    const int bz = rem / gy;
    const int bzh = bz / zdiv, bzl = bz - bzh * zdiv;

    A += sA_hi * bzh + sA * bzl;
    Bt += sB_hi * bzh + sB * bzl;
    const int m0 = by * 128, n0 = bx * 128;

    __shared__ char lds[65536];  // 2 buffers x (A 16K | B 16K)

    const int t = threadIdx.x, l = t & 63, w = t >> 6;  // w 0..7
    const int wm = w >> 1, wn = w & 1;                  // 4x2 wave grid

    f32x4 acc[2][4] = {};

    // staging: wave w stages 16 rows of A and B; lane l -> row +(l>>3),
    // LDS granule (l&7) gets source granule (l&7)^(row&7)
    const int g2 = (((l & 7) ^ (l >> 3)) << 4);
    const long long la2 = (long long)lda * 2, lb2 = (long long)ldb * 2;
    const char* Agp = (const char*)A + (long long)(m0 + w * 16 + (l >> 3)) * la2 + g2;
    const char* Bgp = (const char*)Bt + (long long)(n0 + w * 16 + (l >> 3)) * lb2 + g2;

    // fragment reads: row ...+fr, granule g=ks*4+qh at slot g^(row&7)
    const int fr = l & 15, qh = l >> 4, sx = l & 7;
    int offA[2][2], offB[2][4];
#pragma unroll
    for (int ks = 0; ks < 2; ++ks) {
        const int swz = (((ks << 2) | qh) ^ sx) << 4;
#pragma unroll
        for (int i = 0; i < 2; ++i)
            offA[ks][i] = (wm * 32 + i * 16 + fr) * 128 + swz;
#pragma unroll
        for (int j = 0; j < 4; ++j)
            offB[ks][j] = 16384 + (wn * 64 + j * 16 + fr) * 128 + swz;
    }

#define STAGE(kt, bufo)                                                        \
    {                                                                          \
        const long long kb = (long long)(kt) * 128;                            \
        char* lA = lds + (bufo) + w * 2048;                                    \
        char* lB = lds + (bufo) + 16384 + w * 2048;                            \
        GLOAD16(Agp + kb, lA);                                                 \
        GLOAD16(Agp + kb + 8 * la2, lA + 1024);                                \
        GLOAD16(Bgp + kb, lB);                                                 \
        GLOAD16(Bgp + kb + 8 * lb2, lB + 1024);                                \
    }

    const int KT = K >> 6;
    STAGE(0, 0);
    __syncthreads();
    for (int kt = 0; kt < KT; ++kt) {
        const int cur = (kt & 1) << 15;
        if (kt + 1 < KT) STAGE(kt + 1, cur ^ 32768);
#pragma unroll
        for (int ks = 0; ks < 2; ++ks) {
            bf16x8 af[2], bfr[4];
#pragma unroll
            for (int i = 0; i < 2; ++i) af[i] = *(const bf16x8*)(lds + cur + offA[ks][i]);
#pragma unroll
            for (int j = 0; j < 4; ++j) bfr[j] = *(const bf16x8*)(lds + cur + offB[ks][j]);
#pragma unroll
            for (int i = 0; i < 2; ++i)
#pragma unroll
                for (int j = 0; j < 4; ++j)
                    acc[i][j] = __builtin_amdgcn_mfma_f32_16x16x32_bf16(
                        af[i], bfr[j], acc[i][j], 0, 0, 0);
        }
        __syncthreads();
    }
#undef STAGE

    // C/D frag: col = n0+wn*64+j*16+(l&15), row = m0+wm*32+i*16+(l>>4)*4+r
    const int crow0 = m0 + wm * 32 + (l >> 4) * 4;
    const int ccol0 = n0 + wn * 64 + fr;

    if (MODE == 1) {
        const float4* pr = posr + bzl * Ss;
        const float* uv = uvec + (long long)bzh * BS + bzl * Ss;
        const float* vv = vvec + (long long)bzh * BS + bzl * Ss;
        const float cadd = cptr[bzh];
        const float thr = 0.2f * (float)(*OWp);
        float4 pm[4];
        float vj[4];
#pragma unroll
        for (int j = 0; j < 4; ++j) {
            pm[j] = pr[ccol0 + j * 16];
            vj[j] = vv[ccol0 + j * 16];
        }
        float* Cf = (float*)Cv + sC * bzl;
        __bf16* Cb = obf_out + sOb * bzh + sC * bzl;
        const int as_bf = (bzh < nbf);
#pragma unroll
        for (int i = 0; i < 2; ++i)
#pragma unroll
            for (int r = 0; r < 4; ++r) {
                int row = crow0 + i * 16 + r;
                float4 pn = pr[row];
                float un = uv[row];
#pragma unroll
                for (int j = 0; j < 4; ++j) {
                    float e = fmaf(pn.y, pm[j].y, pn.x * pm[j].x);
                    float d2 = __fadd_rn(__fsub_rn(pn.z, __fmul_rn(2.0f, e)), pm[j].z);
                    float dist = sqrtf(fmaxf(d2, 0.0f));
                    float ov = (acc[i][j][r] + un + vj[j] + cadd) * scale;
                    if (dist > thr) ov = -INFINITY;
                    if (as_bf) Cb[(long long)row * ldc + ccol0 + j * 16] = (__bf16)ov;
                    else       Cf[(long long)row * ldc + ccol0 + j * 16] = ov;
                }
            }
    } else if (MODE == 2) {
        __bf16* C = (__bf16*)Cv + sC_hi * bzh + sC * bzl;
#pragma unroll
        for (int j = 0; j < 4; ++j)
#pragma unroll
            for (int i = 0; i < 2; ++i)
#pragma unroll
                for (int r = 0; r < 4; ++r) {
                    int row = crow0 + i * 16 + r;
                    C[(long long)row * ldc + ccol0 + j * 16] = (__bf16)acc[i][j][r];
                }
    } else {
        __bf16* C = (__bf16*)Cv + sC_hi * bzh + sC * bzl;
        float s = 0.f, ss = 0.f;
#pragma unroll
        for (int j = 0; j < 4; ++j)
#pragma unroll
            for (int i = 0; i < 2; ++i)
#pragma unroll
                for (int r = 0; r < 4; ++r) {
                    int row = crow0 + i * 16 + r;
                    float ov = acc[i][j][r];
                    C[(long long)row * ldc + ccol0 + j * 16] = (__bf16)ov;
                    s += ov;
                    ss = fmaf(ov, ov, ss);
                }
#pragma unroll
        for (int o = 32; o > 0; o >>= 1) {
            s += __shfl_down(s, o);
            ss += __shfl_down(ss, o);
        }
        float* redf = (float*)lds;
        if (l == 0) { redf[w * 2] = s; redf[w * 2 + 1] = ss; }
        __syncthreads();
        if (t == 0) {
            float S = 0.f, SS = 0.f;
#pragma unroll
            for (int ww = 0; ww < 8; ++ww) { S += redf[ww * 2]; SS += redf[ww * 2 + 1]; }
            atomicAdd(&statsraw[(bzh * zdiv + bzl) * 2], S);
            atomicAdd(&statsraw[(bzh * zdiv + bzl) * 2 + 1], SS);
        }
    }
}

// ---------------------------------------------------------------------------
// Wave-per-row softmax, rows of 1280. 256 threads = 4 waves = 4 rows/block.
// INBF=1: bf16 in-place (iobf). INBF=0: f32 in-place (f32io) + bf16 out (bfout).
// All loads/stores vectorized (bf16x4 / float4); row lives in 20 regs/lane.
// ---------------------------------------------------------------------------
template <int INBF>
__global__ __launch_bounds__(256) void softmax_rows(
    __bf16* __restrict__ iobf, float* __restrict__ f32io,
    __bf16* __restrict__ bfout) {
    const int row = blockIdx.x * 4 + (threadIdx.x >> 6);
    const int l = threadIdx.x & 63;

    float vals[20];
    float m = -INFINITY;
    if (INBF) {
        const __bf16* p = iobf + (long long)row * Ss;
#pragma unroll
        for (int c = 0; c < 5; ++c) {
            bf16x4v v = *(const bf16x4v*)(p + (c * 64 + l) * 4);
#pragma unroll
            for (int e = 0; e < 4; ++e) {
                float f = (float)v[e];
                vals[c * 4 + e] = f;
                m = fmaxf(m, f);
            }
        }
    } else {
        const float4* p = (const float4*)(f32io + (long long)row * Ss);
#pragma unroll
        for (int c = 0; c < 5; ++c) {
            float4 v = p[c * 64 + l];
            vals[c * 4 + 0] = v.x; vals[c * 4 + 1] = v.y;
            vals[c * 4 + 2] = v.z; vals[c * 4 + 3] = v.w;
            m = fmaxf(fmaxf(m, fmaxf(v.x, v.y)), fmaxf(v.z, v.w));
        }
    }
#pragma unroll
    for (int o = 32; o > 0; o >>= 1) m = fmaxf(m, __shfl_xor(m, o));

    float s = 0.f;
#pragma unroll
    for (int e = 0; e < 20; ++e) {
        float ev = expf(vals[e] - m);
        vals[e] = ev;
        s += ev;
    }
#pragma unroll
    for (int o = 32; o > 0; o >>= 1) s += __shfl_xor(s, o);
    const float inv = 1.0f / s;

    if (INBF) {
        __bf16* p = iobf + (long long)row * Ss;
#pragma unroll
        for (int c = 0; c < 5; ++c) {
            bf16x4v o;
#pragma unroll
            for (int e = 0; e < 4; ++e) o[e] = (__bf16)(vals[c * 4 + e] * inv);
            *(bf16x4v*)(p + (c * 64 + l) * 4) = o;
        }
    } else {
        float4* p = (float4*)(f32io + (long long)row * Ss);
        __bf16* q = bfout + (long long)row * Ss;
#pragma unroll
        for (int c = 0; c < 5; ++c) {
            float4 ov;
            ov.x = vals[c * 4 + 0] * inv; ov.y = vals[c * 4 + 1] * inv;
            ov.z = vals[c * 4 + 2] * inv; ov.w = vals[c * 4 + 3] * inv;
            p[c * 64 + l] = ov;
            bf16x4v ob;
            ob[0] = (__bf16)ov.x; ob[1] = (__bf16)ov.y;
            ob[2] = (__bf16)ov.z; ob[3] = (__bf16)ov.w;
            *(bf16x4v*)(q + (c * 64 + l) * 4) = ob;
        }
    }
}

// ---------------------------------------------------------------------------
// finalize 16 (graph-slot, batch) LN stats; reset raw accumulators
// ---------------------------------------------------------------------------
__global__ void stats_final(float* __restrict__ raw, float2* __restrict__ stats) {
    const int b = threadIdx.x;
    if (b < 16) {
        float S = raw[b * 2], SS = raw[b * 2 + 1];
        const float invn = 1.0f / (float)SC;
        float mu = S * invn;
        float var = SS * invn - mu * mu;
        stats[b] = make_float2(mu, 1.0f / sqrtf(var + 1e-5f));
        raw[b * 2] = 0.f;
        raw[b * 2 + 1] = 0.f;
    }
}

// ---------------------------------------------------------------------------
// out (+)= relu(LN(agg_g0)) + relu(LN(agg_g1))  (pair, bf16 agg)
// ---------------------------------------------------------------------------
__global__ __launch_bounds__(256) void ln_relu2(
    const __bf16* __restrict__ agg, const float2* __restrict__ stats,
    const float* __restrict__ lnsc, const float* __restrict__ lnbi,
    float* __restrict__ out, int first) {
    for (int idx = blockIdx.x * 256 + threadIdx.x; idx < OUT0 / 4;
         idx += gridDim.x * 256) {
        int b = idx / (SC / 4);
        int j = idx - b * (SC / 4);
        float2 s0 = stats[b], s1 = stats[8 + b];
        bf16x4v a0 = ((const bf16x4v*)agg)[idx];
        bf16x4v a1 = ((const bf16x4v*)agg)[idx + OUT0 / 4];
        float4 c0 = ((const float4*)lnsc)[j];
        float4 c1 = ((const float4*)(lnsc + SC))[j];
        float4 bi0 = ((const float4*)lnbi)[j];
        float4 bi1 = ((const float4*)(lnbi + SC))[j];
        float4 o;
        o.x = fmaxf(((float)a0[0] - s0.x) * s0.y * c0.x + bi0.x, 0.f)
            + fmaxf(((float)a1[0] - s1.x) * s1.y * c1.x + bi1.x, 0.f);
        o.y = fmaxf(((float)a0[1] - s0.x) * s0.y * c0.y + bi0.y, 0.f)
            + fmaxf(((float)a1[1] - s1.x) * s1.y * c1.y + bi1.y, 0.f);
        o.z = fmaxf(((float)a0[2] - s0.x) * s0.y * c0.z + bi0.z, 0.f)
            + fmaxf(((float)a1[2] - s1.x) * s1.y * c1.z + bi1.z, 0.f);
        o.w = fmaxf(((float)a0[3] - s0.x) * s0.y * c0.w + bi0.w, 0.f)
            + fmaxf(((float)a1[3] - s1.x) * s1.y * c1.w + bi1.w, 0.f);
        float4* op = (float4*)out + idx;
        if (!first) {
            float4 pv = *op;
            o.x += pv.x; o.y += pv.y; o.z += pv.z; o.w += pv.w;
        }
        *op = o;
    }
}

// ---------------------------------------------------------------------------
extern "C" void kernel_launch(void* const* d_in, const int* in_sizes, int n_in,
                              void* d_out, int out_size, void* d_ws, size_t ws_size,
                              hipStream_t stream) {
    const float* x        = (const float*)d_in[0];
    const float* box      = (const float*)d_in[1];
    const float* W_theta  = (const float*)d_in[2];
    const float* b_theta  = (const float*)d_in[3];
    const float* W_phi    = (const float*)d_in[4];
    const float* b_phi    = (const float*)d_in[5];
    const float* W_gcn    = (const float*)d_in[6];
    const float* ln_scale = (const float*)d_in[7];
    const float* ln_bias  = (const float*)d_in[8];
    const int*   OWp      = (const int*)d_in[10];

    float* out = (float*)d_out;            // [8,1280,512]
    float* rel_f32 = out + OUT0;           // [8,1280,1280] (output 1 region)

    char* ws = (char*)d_ws;
    float4* posr   = (float4*)(ws + 0);                 //   163840
    __bf16* x_bf   = (__bf16*)(ws + 163840);            // 10485760 [10240][512]
    __bf16* Wgt    = (__bf16*)(ws + 10649600);          //  6291456 [12][512][512]
    __bf16* GiT    = (__bf16*)(ws + 16941056);          //  6291456 [12][512][512]
    float*  w1w2   = (float*)(ws + 23232512);           //    49152
    float*  cvals  = (float*)(ws + 23281664);           //      256
    float*  u      = (float*)(ws + 23281920);           //   491520 [12][10240]
    float*  v      = (float*)(ws + 23773440);           //   491520
    float*  sraw   = (float*)(ws + 24264960);           //      128 (16 slots)
    float2* stats  = (float2*)(ws + 24265088);          //      128
    __bf16* ybuf   = (__bf16*)(ws + 24265216);          // 20971520 [2][10240][512]
    __bf16* z_all  = (__bf16*)(ws + 45236736);          // 125829120 [12][8][512][1280]
    __bf16* Sbuf   = (__bf16*)(ws + 171065856);         // 52428800 [2][8][1280][1280]
    __bf16* aggB   = (__bf16*)(ws + 223494656);         // 20971520 [2][10240][512]
    // prep-only aliases (dead once loop starts)
    __bf16* Wth_bf = (__bf16*)(ws + 244466176);         //  6291456
    __bf16* Wph_bf = (__bf16*)(ws + 250757632);         //  6291456

    hipMemsetAsync(sraw, 0, 128, stream);

    // ---- one-time prep ----
    compute_pos<<<dim3(40), dim3(256), 0, stream>>>(box, posr);
    cvt_bf16<<<dim3(2048), dim3(256), 0, stream>>>(x, x_bf, OUT0 / 4);
    cvt_bf16<<<dim3(2048), dim3(256), 0, stream>>>(W_theta, Wth_bf, 786432);
    cvt_bf16<<<dim3(2048), dim3(256), 0, stream>>>(W_phi, Wph_bf, 786432);
    transpose_cvt<<<dim3(8, 8, 12), dim3(256), 0, stream>>>(
        W_gcn, Wgt, Cc, Cc, (long long)Cc * Cc, (long long)Cc * Cc);
    // GiT[i][d][c] = sum_f Wphi[d][f] * Wtheta[c][f]
    gemm_bf16<2><<<dim3(4, 4, 12), dim3(512), 0, stream>>>(
        Wph_bf, Wth_bf, GiT, Cc, Cc, Cc, Cc, 1,
        262144, 0, 262144, 0, 262144, 0,
        nullptr, nullptr, nullptr, nullptr, nullptr, 0.f, nullptr, 0, 0, nullptr);
    // bias rank-1 terms (exact; zeros for this input)
    uvc_w<<<dim3(128, 12), dim3(256), 0, stream>>>(W_theta, W_phi, b_theta, b_phi, w1w2);
    cvals_k<<<dim3(12), dim3(64), 0, stream>>>(b_theta, b_phi, cvals);
    uvc_x<<<dim3(2560), dim3(256), 0, stream>>>(x, w1w2, u, v);
    // z_all[i][b][c][s] = sum_f Wgt_i[c][f] * x_b[s][f]
    gemm_bf16<2><<<dim3(10, 4, 96), dim3(512), 0, stream>>>(
        Wgt, x_bf, z_all, Cc, Cc, Ss, Cc, 8,
        262144, 0, 0, (long long)SC, (long long)Bb * Cc * Ss, (long long)Cc * Ss,
        nullptr, nullptr, nullptr, nullptr, nullptr, 0.f, nullptr, 0, 0, nullptr);

    const float inv_sqrt = 0.044194173824159216f;  // 1/sqrt(512)

    for (int g = 0; g < 6; ++g) {
        const int i0 = g * 2;
        const int lastg = (g == 5);
        // y pair: ybuf[s][m][c] = x @ G_{i0+s}
        gemm_bf16<2><<<dim3(4, 80, 2), dim3(512), 0, stream>>>(
            x_bf, GiT + (long long)i0 * Cc * Cc, ybuf, Cc, Cc, Cc, Cc, 1,
            0, 0, 262144, 0, (long long)BS * Cc, 0,
            nullptr, nullptr, nullptr, nullptr, nullptr, 0.f, nullptr, 0, 0, nullptr);
        // sim pair = (y @ x^T + u + v + c)*scale, masked -> Sbuf (bf16);
        // last graph's slot1 goes f32 to rel_f32 instead (exact relation path)
        gemm_bf16<1><<<dim3(10, 10, 16), dim3(512), 0, stream>>>(
            ybuf, x_bf, rel_f32, Cc, Cc, Ss, Cc, 8,
            (long long)BS * Cc, (long long)Ss * Cc, 0, (long long)Ss * Cc,
            0, (long long)Ss * Ss,
            u + (long long)i0 * BS, v + (long long)i0 * BS, cvals + i0,
            posr, OWp, inv_sqrt, Sbuf, (long long)BS * Ss, lastg ? 1 : 2, nullptr);
        // softmax in place on Sbuf (wave-per-row, vectorized)
        if (!lastg) {
            softmax_rows<1><<<dim3(2 * BS / 4), dim3(256), 0, stream>>>(
                Sbuf, nullptr, nullptr);
        } else {
            softmax_rows<1><<<dim3(BS / 4), dim3(256), 0, stream>>>(
                Sbuf, nullptr, nullptr);
            softmax_rows<0><<<dim3(BS / 4), dim3(256), 0, stream>>>(
                nullptr, rel_f32, Sbuf + (long long)BS * Ss);
        }
        // agg pair = P @ z -> bf16 (+ fused LN partial stats in f32)
        gemm_bf16<3><<<dim3(4, 10, 16), dim3(512), 0, stream>>>(
            Sbuf, z_all + (long long)i0 * Bb * Cc * Ss, aggB,
            Ss, Ss, Cc, Ss, 8,
            (long long)BS * Ss, (long long)Ss * Ss,
            (long long)Bb * Cc * Ss, (long long)Cc * Ss,
            (long long)BS * Cc, (long long)SC,
            nullptr, nullptr, nullptr, nullptr, nullptr, 0.f, nullptr, 0, 0, sraw);
        // finalize pair stats (and reset raw accumulators)
        stats_final<<<dim3(1), dim3(64), 0, stream>>>(sraw, stats);
        // out (+)= relu(LN(agg0)) + relu(LN(agg1))
        ln_relu2<<<dim3(2048), dim3(256), 0, stream>>>(
            aggB, stats, ln_scale + (long long)i0 * SC, ln_bias + (long long)i0 * SC,
            out, g == 0 ? 1 : 0);
    }
}